// Round 3
// baseline (388.619 us; speedup 1.0000x reference)
//
#include <hip/hip_runtime.h>
#include <math.h>

#define BB 4
#define CC 256
#define OO 256
#define AA 9
#define HH 96
#define WW 96
#define HW (HH*WW)          // 9216
#define HIDN 18
#define EPS 1e-5f

__device__ __forceinline__ float sigmoidf_(float x) { return 1.0f / (1.0f + __expf(-x)); }
__device__ __forceinline__ float siluf_(float x)    { return x * sigmoidf_(x); }

// ---------------------------------------------------------------------------
// Kernel 1: per-(b,c) fused gate + depthwise 3x3 experts + InstanceNorm + SiLU
//           + gated weighted sum over experts  -> moe[b][c][h][w]
// One block per (b,c). x plane staged in LDS with zero halo. Two conv passes:
// pass1 = per-expert sum/sumsq (IN stats), pass2 = normalize+silu+weighted sum.
// ---------------------------------------------------------------------------
__global__ __launch_bounds__(256)
void k_moe(const float* __restrict__ x,
           const float* __restrict__ w_expert,
           const float* __restrict__ w_g1, const float* __restrict__ b_g1,
           const float* __restrict__ w_g2, const float* __restrict__ b_g2,
           float* __restrict__ moe)
{
    __shared__ float tile[98 * 98];      // 38.4 KB, zero halo
    __shared__ float wexp[81];
    __shared__ float pool[9];            // region sums
    __shared__ float hbuf[HIDN];
    __shared__ float wgt[9];
    __shared__ float stat[18];           // sum[9], sumsq[9]
    __shared__ float mu_s[9], rstd_s[9];

    const int bc  = blockIdx.x;          // b*C + c
    const int c   = bc & (CC - 1);
    const int tid = threadIdx.x;

    // zero LDS tile (halo) + small buffers
    for (int i = tid; i < 98 * 98; i += 256) tile[i] = 0.0f;
    if (tid < 18) stat[tid] = 0.0f;
    if (tid < 9)  pool[tid] = 0.0f;
    if (tid < 81) wexp[tid] = w_expert[c * 81 + tid];
    __syncthreads();

    // load x plane into interior
    const float* xp = x + (size_t)bc * HW;
    for (int i = tid; i < HW; i += 256) {
        int r = i / 96, col = i - r * 96;
        tile[(r + 1) * 98 + col + 1] = xp[i];
    }
    __syncthreads();

    // ---- pooled 3x3 block means (regions of 32x32) ----
    for (int r = 0; r < 9; ++r) {
        const int i0 = (r / 3) * 32, j0 = (r % 3) * 32;
        float s = 0.0f;
        for (int idx = tid; idx < 1024; idx += 256) {
            int rr = idx >> 5, cc2 = idx & 31;
            s += tile[(i0 + rr + 1) * 98 + (j0 + cc2 + 1)];
        }
        #pragma unroll
        for (int off = 1; off < 64; off <<= 1) s += __shfl_xor(s, off, 64);
        if ((tid & 63) == 0) atomicAdd(&pool[r], s);
    }
    __syncthreads();

    // ---- gate MLP: 9 -> 18 (SiLU) -> 9 (sigmoid) ----
    if (tid < HIDN) {
        float acc = b_g1[tid];
        #pragma unroll
        for (int j = 0; j < 9; ++j)
            acc += (pool[j] * (1.0f / 1024.0f)) * w_g1[tid * 9 + j];
        hbuf[tid] = siluf_(acc);
    }
    __syncthreads();
    if (tid < 9) {
        float acc = b_g2[tid];
        #pragma unroll
        for (int k = 0; k < HIDN; ++k) acc += hbuf[k] * w_g2[tid * HIDN + k];
        wgt[tid] = sigmoidf_(acc);
    }
    __syncthreads();

    // expert weights -> registers (static indexing, stays in VGPRs)
    float wre[81];
    #pragma unroll
    for (int i = 0; i < 81; ++i) wre[i] = wexp[i];

    // ---- pass 1: conv -> per-expert sum / sumsq ----
    float sum[9], sq[9];
    #pragma unroll
    for (int a = 0; a < 9; ++a) { sum[a] = 0.0f; sq[a] = 0.0f; }

    for (int i = tid; i < HW; i += 256) {
        int r = i / 96, col = i - r * 96;
        const float* bp = &tile[r * 98 + col];   // top-left of 3x3 window
        float n0 = bp[0],   n1 = bp[1],   n2 = bp[2];
        float n3 = bp[98],  n4 = bp[99],  n5 = bp[100];
        float n6 = bp[196], n7 = bp[197], n8 = bp[198];
        #pragma unroll
        for (int a = 0; a < 9; ++a) {
            float v = n0 * wre[a*9+0] + n1 * wre[a*9+1] + n2 * wre[a*9+2]
                    + n3 * wre[a*9+3] + n4 * wre[a*9+4] + n5 * wre[a*9+5]
                    + n6 * wre[a*9+6] + n7 * wre[a*9+7] + n8 * wre[a*9+8];
            sum[a] += v;
            sq[a]  += v * v;
        }
    }
    #pragma unroll
    for (int a = 0; a < 9; ++a) {
        float s = sum[a], q = sq[a];
        #pragma unroll
        for (int off = 1; off < 64; off <<= 1) {
            s += __shfl_xor(s, off, 64);
            q += __shfl_xor(q, off, 64);
        }
        if ((tid & 63) == 0) { atomicAdd(&stat[a], s); atomicAdd(&stat[9 + a], q); }
    }
    __syncthreads();
    if (tid < 9) {
        float m = stat[tid] * (1.0f / HW);
        float v = stat[9 + tid] * (1.0f / HW) - m * m;
        mu_s[tid]   = m;
        rstd_s[tid] = rsqrtf(v + EPS);
    }
    __syncthreads();

    // hoist stats + gate weights to registers
    float mu_r[9], rs_r[9], wg_r[9];
    #pragma unroll
    for (int a = 0; a < 9; ++a) { mu_r[a] = mu_s[a]; rs_r[a] = rstd_s[a]; wg_r[a] = wgt[a]; }

    // ---- pass 2: conv -> IN -> SiLU -> gated sum -> moe ----
    float* mp = moe + (size_t)bc * HW;
    for (int i = tid; i < HW; i += 256) {
        int r = i / 96, col = i - r * 96;
        const float* bp = &tile[r * 98 + col];
        float n0 = bp[0],   n1 = bp[1],   n2 = bp[2];
        float n3 = bp[98],  n4 = bp[99],  n5 = bp[100];
        float n6 = bp[196], n7 = bp[197], n8 = bp[198];
        float acc = 0.0f;
        #pragma unroll
        for (int a = 0; a < 9; ++a) {
            float v = n0 * wre[a*9+0] + n1 * wre[a*9+1] + n2 * wre[a*9+2]
                    + n3 * wre[a*9+3] + n4 * wre[a*9+4] + n5 * wre[a*9+5]
                    + n6 * wre[a*9+6] + n7 * wre[a*9+7] + n8 * wre[a*9+8];
            float t = (v - mu_r[a]) * rs_r[a];
            acc += wg_r[a] * (t * sigmoidf_(t));
        }
        mp[i] = acc;
    }
}

// ---------------------------------------------------------------------------
// Kernel 2: z[b][o][hw] = sum_c w_proj[o][c] * moe[b][c][hw]  (fp32 GEMM)
//           + per-o partial sum/sumsq for BatchNorm via block-reduce + atomics
// Tile: O=128 x P=128 x Ck=32. 256 threads; thread = (to 0..7, tp 0..31),
// 16 o x 4 px accumulators per thread (16 float4).
// ---------------------------------------------------------------------------
#define OT 128
#define PT 128
#define CKK 32

__global__ __launch_bounds__(256)
void k_gemm(const float* __restrict__ moe, const float* __restrict__ wproj,
            float* __restrict__ z, float* __restrict__ stats)
{
    __shared__ float wl[CKK][OT + 4];    // [c][o], pad to break write conflicts
    __shared__ float ml[CKK][PT];        // [c][p]

    const int pt  = blockIdx.x;          // 0..71
    const int ot  = blockIdx.y;          // 0..1
    const int b   = blockIdx.z;          // 0..3
    const int tid = threadIdx.x;
    const int to  = tid >> 5;            // 0..7  (16 o's each)
    const int tp  = tid & 31;            // 0..31 (4 px each)
    const int p0  = pt * PT, o0 = ot * OT;

    float4 acc[16];
    #pragma unroll
    for (int i = 0; i < 16; ++i) acc[i] = make_float4(0.f, 0.f, 0.f, 0.f);

    for (int c0 = 0; c0 < CC; c0 += CKK) {
        // w tile: 128 o x 32 c (consecutive lanes read consecutive c)
        #pragma unroll
        for (int i = 0; i < 16; ++i) {
            int idx = tid + i * 256;
            int cc  = idx & (CKK - 1);
            int oo  = idx >> 5;
            wl[cc][oo] = wproj[(size_t)(o0 + oo) * CC + c0 + cc];
        }
        // moe tile: 32 c x 128 p (fully coalesced)
        #pragma unroll
        for (int i = 0; i < 16; ++i) {
            int idx = tid + i * 256;
            int pp  = idx & (PT - 1);
            int cc  = idx >> 7;
            ml[cc][pp] = moe[((size_t)b * CC + c0 + cc) * HW + p0 + pp];
        }
        __syncthreads();

        #pragma unroll
        for (int cc = 0; cc < CKK; ++cc) {
            float4 m = *(const float4*)&ml[cc][tp * 4];
            const float* wr = &wl[cc][to * 16];
            float wv[16];
            #pragma unroll
            for (int k = 0; k < 4; ++k) {
                float4 w4 = *(const float4*)(wr + 4 * k);
                wv[4*k+0] = w4.x; wv[4*k+1] = w4.y; wv[4*k+2] = w4.z; wv[4*k+3] = w4.w;
            }
            #pragma unroll
            for (int oi = 0; oi < 16; ++oi) {
                acc[oi].x = fmaf(wv[oi], m.x, acc[oi].x);
                acc[oi].y = fmaf(wv[oi], m.y, acc[oi].y);
                acc[oi].z = fmaf(wv[oi], m.z, acc[oi].z);
                acc[oi].w = fmaf(wv[oi], m.w, acc[oi].w);
            }
        }
        __syncthreads();
    }

    // write z + BN partial stats
    float* zp = z + ((size_t)b * OO + o0 + to * 16) * HW + p0 + tp * 4;
    #pragma unroll
    for (int oi = 0; oi < 16; ++oi) {
        *(float4*)(zp + (size_t)oi * HW) = acc[oi];
        float s = acc[oi].x + acc[oi].y + acc[oi].z + acc[oi].w;
        float q = acc[oi].x * acc[oi].x + acc[oi].y * acc[oi].y
                + acc[oi].z * acc[oi].z + acc[oi].w * acc[oi].w;
        #pragma unroll
        for (int off = 1; off < 32; off <<= 1) {
            s += __shfl_xor(s, off, 64);
            q += __shfl_xor(q, off, 64);
        }
        if (tp == 0) {
            atomicAdd(&stats[o0 + to * 16 + oi], s);
            atomicAdd(&stats[OO + o0 + to * 16 + oi], q);
        }
    }
}

// ---------------------------------------------------------------------------
// Kernel 3: BatchNorm (batch stats) + affine + SiLU, float4 elementwise
// ---------------------------------------------------------------------------
__global__ __launch_bounds__(256)
void k_bnsilu(const float* __restrict__ z, const float* __restrict__ stats,
              const float* __restrict__ gamma, const float* __restrict__ beta,
              float* __restrict__ out)
{
    const float invn = 1.0f / (float)(BB * HW);
    const int n4 = BB * OO * HW / 4;               // 2359296
    for (int i = blockIdx.x * blockDim.x + threadIdx.x; i < n4;
         i += gridDim.x * blockDim.x) {
        int o = (i / (HW / 4)) & (OO - 1);
        float m  = stats[o] * invn;
        float vv = stats[OO + o] * invn - m * m;
        float rs = rsqrtf(vv + EPS);
        float g  = gamma[o] * rs;
        float bb = beta[o] - m * g;
        float4 v = ((const float4*)z)[i];
        v.x = siluf_(fmaf(v.x, g, bb));
        v.y = siluf_(fmaf(v.y, g, bb));
        v.z = siluf_(fmaf(v.z, g, bb));
        v.w = siluf_(fmaf(v.w, g, bb));
        ((float4*)out)[i] = v;
    }
}

// ---------------------------------------------------------------------------
extern "C" void kernel_launch(void* const* d_in, const int* in_sizes, int n_in,
                              void* d_out, int out_size, void* d_ws, size_t ws_size,
                              hipStream_t stream)
{
    const float* x        = (const float*)d_in[0];
    const float* w_expert = (const float*)d_in[1];
    const float* w_g1     = (const float*)d_in[2];
    const float* b_g1     = (const float*)d_in[3];
    const float* w_g2     = (const float*)d_in[4];
    const float* b_g2     = (const float*)d_in[5];
    const float* w_proj   = (const float*)d_in[6];
    const float* bn_g     = (const float*)d_in[7];
    const float* bn_b     = (const float*)d_in[8];
    float* out = (float*)d_out;

    float* z     = (float*)d_ws;                    // B*O*HW floats (37.7 MB)
    float* stats = z + (size_t)BB * OO * HW;        // 2*O floats
    float* moe   = out;                             // reuse d_out as scratch

    hipMemsetAsync(stats, 0, 2 * OO * sizeof(float), stream);

    k_moe<<<BB * CC, 256, 0, stream>>>(x, w_expert, w_g1, b_g1, w_g2, b_g2, moe);
    k_gemm<<<dim3(HW / PT, OO / OT, BB), 256, 0, stream>>>(moe, w_proj, z, stats);
    k_bnsilu<<<2048, 256, 0, stream>>>(z, stats, bn_g, bn_b, out);
}